// Round 7
// baseline (1355.372 us; speedup 1.0000x reference)
//
#include <hip/hip_runtime.h>

// MPNN_edge_sparse_ogb — round 6 (= round 5 + compile fix: ext_vector u16x4 for
// nontemporal store; HIP_vector_type ushort4 is not a clang vector type).
//  - materialize: stream ef in edge order, msg=relu(h[src]+ef)->bf16, append into
//    391 dst-buckets (128 nodes each) via cursor atomics (<=391 write streams).
//  - reduce: block per bucket, 64KB LDS fp32 accumulator, stream msgs, LDS atomics,
//    epilogue z = h + agg -> bf16 zb.
//  - init folds: hp pack, cursor zero, weight pack. 4 dispatches total.
// ws: zb | hp | cursor[391] | msgbuf[391*4096*128]bf16 | dstloc[391*4096]u16 | w1p | w2p

constexpr int DIN  = 96;
constexpr int DDEG = 32;
constexpr int D    = 128;
constexpr int DH   = 256;
constexpr int DUP  = 128;
constexpr int BUCK_SHIFT = 7;               // 128 nodes / bucket
constexpr int BUCK_N     = 1 << BUCK_SHIFT;
constexpr int CAP_SHIFT  = 12;              // 4096 msg slots / bucket (max expected ~2300)
constexpr int CAP        = 1 << CAP_SHIFT;

typedef short bf16x8 __attribute__((ext_vector_type(8)));
typedef float f32x4  __attribute__((ext_vector_type(4)));
typedef unsigned short u16x4 __attribute__((ext_vector_type(4)));

static __device__ __forceinline__ ushort f2bf(float f) {
    unsigned u = __float_as_uint(f);
    unsigned r = (u + 0x7fff + ((u >> 16) & 1)) >> 16;   // RNE
    return (ushort)r;
}
static __device__ __forceinline__ float4 bfv_to_f4(u16x4 u) {
    float4 r;
    r.x = __uint_as_float((unsigned)u.x << 16);
    r.y = __uint_as_float((unsigned)u.y << 16);
    r.z = __uint_as_float((unsigned)u.z << 16);
    r.w = __uint_as_float((unsigned)u.w << 16);
    return r;
}

// ---------------------------------------------------------------- 0. init: hp pack + cursor zero + weight pack
__global__ __launch_bounds__(256) void init_kernel(
    const float* __restrict__ x, const float* __restrict__ deg,
    const float* __restrict__ W1, const float* __restrict__ W2,
    ushort* __restrict__ hp, ushort* __restrict__ w1p, ushort* __restrict__ w2p,
    int* __restrict__ cursor, int N, int nbuck) {
    int t = blockIdx.x * 256 + threadIdx.x;
    if (t < nbuck) cursor[t] = 0;
    if (t < 32768) {
        {   // w1p[((kb*16+nb)*64+l)*8+j] = bf16(W1[kb*32+(l>>4)*8+j][nb*16+(l&15)])
            int j = t & 7, l = (t >> 3) & 63, nb = (t >> 9) & 15, kb = t >> 13;
            w1p[t] = f2bf(W1[(kb * 32 + (l >> 4) * 8 + j) * DH + nb * 16 + (l & 15)]);
        }
        {   // w2p
            int j = t & 7, l = (t >> 3) & 63, nb = (t >> 9) & 7, kb = t >> 12;
            w2p[t] = f2bf(W2[(kb * 32 + (l >> 4) * 8 + j) * DUP + nb * 16 + (l & 15)]);
        }
    }
    if (t >= N * 32) return;
    int n = t >> 5, c = t & 31;
    float4 v;
    if (c < 24) v = *reinterpret_cast<const float4*>(&x[(size_t)n * DIN + c * 4]);
    else        v = *reinterpret_cast<const float4*>(&deg[(size_t)n * DDEG + (c - 24) * 4]);
    u16x4 o;
    o.x = f2bf(v.x); o.y = f2bf(v.y); o.z = f2bf(v.z); o.w = f2bf(v.w);
    *reinterpret_cast<u16x4*>(&hp[(size_t)n * D + c * 4]) = o;
}

// ---------------------------------------------------------------- 1. materialize: stream ef, append bf16 msgs to buckets
__global__ __launch_bounds__(256) void materialize_kernel(
    const ushort* __restrict__ hp, const float* __restrict__ ef,
    const int* __restrict__ ei, int* __restrict__ cursor,
    ushort* __restrict__ msgbuf, ushort* __restrict__ dstloc, int E) {
    const int e = blockIdx.x * 8 + (threadIdx.x >> 5);
    if (e >= E) return;
    const int lane = threadIdx.x & 63;
    const int c = lane & 31;

    int src = ei[e];
    int dst = ei[E + e];
    int b = dst >> BUCK_SHIFT;

    int pos = 0;
    if (c == 0) pos = atomicAdd(&cursor[b], 1);
    pos = __shfl(pos, lane & 32, 64);          // broadcast from half-wave leader
    if (pos >= CAP) return;                     // statistically unreachable safety

    f32x4 fv = __builtin_nontemporal_load(
        reinterpret_cast<const f32x4*>(&ef[(size_t)e * D + c * 4]));
    float4 hs = bfv_to_f4(*reinterpret_cast<const u16x4*>(&hp[(size_t)src * D + c * 4]));

    u16x4 m;
    m.x = f2bf(fmaxf(fv[0] + hs.x, 0.f));
    m.y = f2bf(fmaxf(fv[1] + hs.y, 0.f));
    m.z = f2bf(fmaxf(fv[2] + hs.z, 0.f));
    m.w = f2bf(fmaxf(fv[3] + hs.w, 0.f));

    size_t mp = ((size_t)b << CAP_SHIFT) + pos;
    __builtin_nontemporal_store(m, reinterpret_cast<u16x4*>(&msgbuf[mp * D + c * 4]));
    if (c == 0) dstloc[mp] = (ushort)(dst & (BUCK_N - 1));
}

// ---------------------------------------------------------------- 2. reduce: block per bucket, LDS fp32 accumulate
__global__ __launch_bounds__(512) void reduce_kernel(
    const ushort* __restrict__ hp, const ushort* __restrict__ msgbuf,
    const ushort* __restrict__ dstloc, const int* __restrict__ cursor,
    ushort* __restrict__ zb, int N) {
    __shared__ float acc[BUCK_N * D];           // 64 KB -> 2 blocks/CU
    const int tid = threadIdx.x, b = blockIdx.x;
    const int hw = tid >> 5, c = tid & 31;      // 16 half-waves

#pragma unroll
    for (int i = 0; i < 8; ++i)
        *reinterpret_cast<float4*>(&acc[tid * 32 + i * 4]) = make_float4(0.f, 0.f, 0.f, 0.f);
    __syncthreads();

    int cnt = cursor[b];
    if (cnt > CAP) cnt = CAP;
    for (int p = hw; p < cnt; p += 16) {
        size_t mp = ((size_t)b << CAP_SHIFT) + p;
        int dl = dstloc[mp];
        float4 mv = bfv_to_f4(*reinterpret_cast<const u16x4*>(&msgbuf[mp * D + c * 4]));
        float* ap = &acc[dl * D + c * 4];
        atomicAdd(ap + 0, mv.x);
        atomicAdd(ap + 1, mv.y);
        atomicAdd(ap + 2, mv.z);
        atomicAdd(ap + 3, mv.w);
    }
    __syncthreads();

#pragma unroll
    for (int i = 0; i < 8; ++i) {
        int nl = hw * 8 + i;
        int node = b * BUCK_N + nl;
        if (node < N) {
            float4 h = bfv_to_f4(*reinterpret_cast<const u16x4*>(&hp[(size_t)node * D + c * 4]));
            const float* ap = &acc[nl * D + c * 4];
            u16x4 o;
            o.x = f2bf(h.x + ap[0]);
            o.y = f2bf(h.y + ap[1]);
            o.z = f2bf(h.z + ap[2]);
            o.w = f2bf(h.w + ap[3]);
            *reinterpret_cast<u16x4*>(&zb[(size_t)node * D + c * 4]) = o;
        }
    }
}

// ---------------------------------------------------------------- 3. MFMA MLP: 64 nodes/block, 16/wave
__global__ __launch_bounds__(256) void mlp_mfma_kernel(
    const ushort* __restrict__ zb,
    const ushort* __restrict__ w1p, const float* __restrict__ b1,
    const ushort* __restrict__ w2p, const float* __restrict__ b2,
    float* __restrict__ out, int N) {
    __shared__ ushort u_lds[4][16][DH + 8];
    const int tid = threadIdx.x;
    const int wave = tid >> 6, lane = tid & 63;
    const int m0 = blockIdx.x * 64 + wave * 16;
    const int lr = lane & 15, lg = lane >> 4;

    bf16x8 a1[4];
    int rowA = m0 + lr; if (rowA > N - 1) rowA = N - 1;
    const ushort* zrow = &zb[(size_t)rowA * D + lg * 8];
#pragma unroll
    for (int kb = 0; kb < 4; ++kb)
        a1[kb] = *reinterpret_cast<const bf16x8*>(zrow + kb * 32);

#pragma unroll
    for (int nb = 0; nb < 16; ++nb) {
        f32x4 c = {0.f, 0.f, 0.f, 0.f};
#pragma unroll
        for (int kb = 0; kb < 4; ++kb) {
            bf16x8 b = *reinterpret_cast<const bf16x8*>(&w1p[((kb * 16 + nb) * 64 + lane) * 8]);
            c = __builtin_amdgcn_mfma_f32_16x16x32_bf16(a1[kb], b, c, 0, 0, 0);
        }
        float bias = b1[nb * 16 + lr];
#pragma unroll
        for (int r = 0; r < 4; ++r) {
            float v = fmaxf(c[r] + bias, 0.f);
            u_lds[wave][lg * 4 + r][nb * 16 + lr] = f2bf(v);
        }
    }
    __syncthreads();

    bf16x8 a2[8];
#pragma unroll
    for (int kb = 0; kb < 8; ++kb)
        a2[kb] = *reinterpret_cast<const bf16x8*>(&u_lds[wave][lr][kb * 32 + lg * 8]);

#pragma unroll
    for (int nb = 0; nb < 8; ++nb) {
        f32x4 c = {0.f, 0.f, 0.f, 0.f};
#pragma unroll
        for (int kb = 0; kb < 8; ++kb) {
            bf16x8 b = *reinterpret_cast<const bf16x8*>(&w2p[((kb * 8 + nb) * 64 + lane) * 8]);
            c = __builtin_amdgcn_mfma_f32_16x16x32_bf16(a2[kb], b, c, 0, 0, 0);
        }
        float bias = b2[nb * 16 + lr];
#pragma unroll
        for (int r = 0; r < 4; ++r) {
            int row = m0 + lg * 4 + r;
            if (row < N) out[(size_t)row * DUP + nb * 16 + lr] = c[r] + bias;
        }
    }
}

// ---------------------------------------------------------------- launch
extern "C" void kernel_launch(void* const* d_in, const int* in_sizes, int n_in,
                              void* d_out, int out_size, void* d_ws, size_t ws_size,
                              hipStream_t stream) {
    const float* x   = (const float*)d_in[0];
    const float* dg  = (const float*)d_in[1];
    const float* ef  = (const float*)d_in[2];
    const float* W1  = (const float*)d_in[3];
    const float* b1  = (const float*)d_in[4];
    const float* W2  = (const float*)d_in[5];
    const float* b2  = (const float*)d_in[6];
    const int*   ei  = (const int*)d_in[7];
    float* out = (float*)d_out;

    const int N = in_sizes[0] / DIN;            // 50000
    const int E = in_sizes[7] / 2;              // 800000
    const int nbuck = (N + BUCK_N - 1) >> BUCK_SHIFT;   // 391

    auto align256 = [](size_t v) { return (v + 255) & ~(size_t)255; };
    char* w = (char*)d_ws;
    ushort* zb     = (ushort*)w;  w += align256((size_t)N * D * 2);
    ushort* hp     = (ushort*)w;  w += align256((size_t)N * D * 2);
    int*    cursor = (int*)w;     w += align256((size_t)nbuck * 4);
    ushort* msgbuf = (ushort*)w;  w += align256((size_t)nbuck * CAP * D * 2);   // ~410 MB
    ushort* dstloc = (ushort*)w;  w += align256((size_t)nbuck * CAP * 2);
    ushort* w1p    = (ushort*)w;  w += align256((size_t)D * DH * 2);
    ushort* w2p    = (ushort*)w;  w += align256((size_t)DH * DUP * 2);

    init_kernel<<<(N * 32 + 255) / 256, 256, 0, stream>>>(
        x, dg, W1, W2, hp, w1p, w2p, cursor, N, nbuck);

    materialize_kernel<<<(E + 7) / 8, 256, 0, stream>>>(
        hp, ef, ei, cursor, msgbuf, dstloc, E);

    reduce_kernel<<<nbuck, 512, 0, stream>>>(hp, msgbuf, dstloc, cursor, zb, N);

    mlp_mfma_kernel<<<(N + 63) / 64, 256, 0, stream>>>(zb, w1p, b1, w2p, b2, out, N);
}

// Round 8
// 285.142 us; speedup vs baseline: 4.7533x; 4.7533x over previous
//
#include <hip/hip_runtime.h>

// MPNN_edge_sparse_ogb — round 7: revert to R4 pipeline (bucket experiment failed:
// contended returning atomics + unexplained reduce serialization). Trims:
//  - gather+MLP fused into one kernel (z tile lives in LDS, no zb round-trip)
//  - weight packing folded into init_h (one less dispatch)
// Pipeline: init_h(+wpack,+zero counts) -> count -> scan x3 -> fill -> fused gather+mlp.
// ws: hp[N*128]bf16 | counts | offsets | cursor | eids2[E]int2 | sums | w1p | w2p

constexpr int DIN  = 96;
constexpr int DDEG = 32;
constexpr int D    = 128;
constexpr int DH   = 256;
constexpr int DUP  = 128;

typedef short bf16x8 __attribute__((ext_vector_type(8)));
typedef float f32x4  __attribute__((ext_vector_type(4)));
typedef unsigned short u16x4 __attribute__((ext_vector_type(4)));

static __device__ __forceinline__ ushort f2bf(float f) {
    unsigned u = __float_as_uint(f);
    unsigned r = (u + 0x7fff + ((u >> 16) & 1)) >> 16;   // RNE
    return (ushort)r;
}
static __device__ __forceinline__ float4 bfv_to_f4(u16x4 u) {
    float4 r;
    r.x = __uint_as_float((unsigned)u.x << 16);
    r.y = __uint_as_float((unsigned)u.y << 16);
    r.z = __uint_as_float((unsigned)u.z << 16);
    r.w = __uint_as_float((unsigned)u.w << 16);
    return r;
}

static __device__ __forceinline__ int waveInclScan(int v, int lane) {
#pragma unroll
    for (int off = 1; off < 64; off <<= 1) {
        int t = __shfl_up(v, off, 64);
        if (lane >= off) v += t;
    }
    return v;
}

// ---------------------------------------------------------------- 0. init: hp pack + zero counts + weight pack
__global__ __launch_bounds__(256) void init_h_kernel(
    const float* __restrict__ x, const float* __restrict__ deg,
    const float* __restrict__ W1, const float* __restrict__ W2,
    ushort* __restrict__ hp, ushort* __restrict__ w1p, ushort* __restrict__ w2p,
    int* __restrict__ counts, int N) {
    int t = blockIdx.x * 256 + threadIdx.x;
    if (t < (N >> 2)) *reinterpret_cast<int4*>(&counts[t * 4]) = make_int4(0, 0, 0, 0);
    if (t == (N >> 2) && (N & 3)) {
        for (int i = (N & ~3); i < N; ++i) counts[i] = 0;
    }
    if (t < 32768) {
        {   // w1p[((kb*16+nb)*64+l)*8+j] = bf16(W1[kb*32+(l>>4)*8+j][nb*16+(l&15)])
            int j = t & 7, l = (t >> 3) & 63, nb = (t >> 9) & 15, kb = t >> 13;
            w1p[t] = f2bf(W1[(kb * 32 + (l >> 4) * 8 + j) * DH + nb * 16 + (l & 15)]);
        }
        {   // w2p: kb<8, nb<8
            int j = t & 7, l = (t >> 3) & 63, nb = (t >> 9) & 7, kb = t >> 12;
            w2p[t] = f2bf(W2[(kb * 32 + (l >> 4) * 8 + j) * DUP + nb * 16 + (l & 15)]);
        }
    }
    if (t >= N * 32) return;
    int n = t >> 5, c = t & 31;
    float4 v;
    if (c < 24) v = *reinterpret_cast<const float4*>(&x[(size_t)n * DIN + c * 4]);
    else        v = *reinterpret_cast<const float4*>(&deg[(size_t)n * DDEG + (c - 24) * 4]);
    u16x4 o;
    o.x = f2bf(v.x); o.y = f2bf(v.y); o.z = f2bf(v.z); o.w = f2bf(v.w);
    *reinterpret_cast<u16x4*>(&hp[(size_t)n * D + c * 4]) = o;
}

// ---------------------------------------------------------------- 1. count in-degrees
__global__ __launch_bounds__(256) void count_kernel(
    const int* __restrict__ ei, int* __restrict__ counts, int N, int E) {
    int e = blockIdx.x * 256 + threadIdx.x;
    if (e >= E) return;
    atomicAdd(&counts[ei[E + e]], 1);
}

// ---------------------------------------------------------------- 2a. per-1024-block sums
__global__ __launch_bounds__(256) void scan_partial_kernel(
    const int* __restrict__ counts, int* __restrict__ blockSums, int N) {
    const int tid = threadIdx.x;
    int base = blockIdx.x * 1024 + tid * 4;
    int4 c = make_int4(0, 0, 0, 0);
    if (base + 3 < N) c = *reinterpret_cast<const int4*>(&counts[base]);
    else if (base < N) {
        c.x = counts[base];
        if (base + 1 < N) c.y = counts[base + 1];
        if (base + 2 < N) c.z = counts[base + 2];
    }
    int s = c.x + c.y + c.z + c.w;
#pragma unroll
    for (int off = 32; off; off >>= 1) s += __shfl_xor(s, off, 64);
    __shared__ int wsum[4];
    if ((tid & 63) == 0) wsum[tid >> 6] = s;
    __syncthreads();
    if (tid == 0) blockSums[blockIdx.x] = wsum[0] + wsum[1] + wsum[2] + wsum[3];
}

// ---------------------------------------------------------------- 2b. scan block sums (<=64)
__global__ __launch_bounds__(64) void scan_base_kernel(
    const int* __restrict__ blockSums, int* __restrict__ blockBase, int nb) {
    int l = threadIdx.x;
    int orig = (l < nb) ? blockSums[l] : 0;
    int incl = waveInclScan(orig, l);
    if (l < nb) blockBase[l] = incl - orig;
}

// ---------------------------------------------------------------- 2c. final scan -> offsets/cursor
__global__ __launch_bounds__(256) void scan_final_kernel(
    const int* __restrict__ counts, const int* __restrict__ blockBase,
    int* __restrict__ offsets, int* __restrict__ cursor, int N, int E) {
    const int tid = threadIdx.x, lane = tid & 63, wave = tid >> 6;
    int base = blockIdx.x * 1024 + tid * 4;
    int4 c = make_int4(0, 0, 0, 0);
    if (base + 3 < N) c = *reinterpret_cast<const int4*>(&counts[base]);
    else if (base < N) {
        c.x = counts[base];
        if (base + 1 < N) c.y = counts[base + 1];
        if (base + 2 < N) c.z = counts[base + 2];
    }
    int s = c.x + c.y + c.z + c.w;
    int incl = waveInclScan(s, lane);
    __shared__ int wsum[4];
    if (lane == 63) wsum[wave] = incl;
    __syncthreads();
    int wb = 0;
#pragma unroll
    for (int w = 0; w < 4; ++w)
        if (w < wave) wb += wsum[w];
    int ex = blockBase[blockIdx.x] + wb + (incl - s);
    if (base < N)     { offsets[base]     = ex; cursor[base]     = ex; } ex += c.x;
    if (base + 1 < N) { offsets[base + 1] = ex; cursor[base + 1] = ex; } ex += c.y;
    if (base + 2 < N) { offsets[base + 2] = ex; cursor[base + 2] = ex; } ex += c.z;
    if (base + 3 < N) { offsets[base + 3] = ex; cursor[base + 3] = ex; }
    if (blockIdx.x == 0 && tid == 0) offsets[N] = E;
}

// ---------------------------------------------------------------- 3. fill CSR payload {e, src}
__global__ __launch_bounds__(256) void fill_kernel(
    const int* __restrict__ ei, int* __restrict__ cursor,
    int2* __restrict__ eids2, int E) {
    int e = blockIdx.x * 256 + threadIdx.x;
    if (e >= E) return;
    int src = ei[e];
    int dst = ei[E + e];
    int pos = atomicAdd(&cursor[dst], 1);
    eids2[pos] = make_int2(e, src);
}

// ---------------------------------------------------------------- 4. fused gather + MFMA MLP, 64 nodes/block
__global__ __launch_bounds__(256) void gather_mlp_kernel(
    const ushort* __restrict__ hp, const float* __restrict__ ef,
    const int* __restrict__ offsets, const int2* __restrict__ eids2,
    const ushort* __restrict__ w1p, const float* __restrict__ b1,
    const ushort* __restrict__ w2p, const float* __restrict__ b2,
    float* __restrict__ out, int N) {
    __shared__ ushort zs[64][D];              // 16 KB z tile (bf16)
    __shared__ ushort u_lds[4][16][DH + 8];   // 33 KB
    const int tid = threadIdx.x;
    const int m0 = blockIdx.x * 64;

    // ---- gather phase: half-wave hw handles local nodes hw*8 .. hw*8+7
    {
        const int hw = tid >> 5, c = tid & 31;
        for (int i = 0; i < 8; ++i) {
            int nl = hw * 8 + i;
            int node = m0 + nl;
            if (node >= N) break;
            float4 h = bfv_to_f4(*reinterpret_cast<const u16x4*>(&hp[(size_t)node * D + c * 4]));
            float4 acc = make_float4(0.f, 0.f, 0.f, 0.f);
            const int pEnd = offsets[node + 1];
            int p = offsets[node];
            for (; p + 4 <= pEnd; p += 4) {
                int2 i0 = eids2[p + 0];
                int2 i1 = eids2[p + 1];
                int2 i2 = eids2[p + 2];
                int2 i3 = eids2[p + 3];
                f32x4 f0 = __builtin_nontemporal_load(
                    reinterpret_cast<const f32x4*>(&ef[(size_t)i0.x * D + c * 4]));
                f32x4 f1 = __builtin_nontemporal_load(
                    reinterpret_cast<const f32x4*>(&ef[(size_t)i1.x * D + c * 4]));
                f32x4 f2 = __builtin_nontemporal_load(
                    reinterpret_cast<const f32x4*>(&ef[(size_t)i2.x * D + c * 4]));
                f32x4 f3 = __builtin_nontemporal_load(
                    reinterpret_cast<const f32x4*>(&ef[(size_t)i3.x * D + c * 4]));
                float4 h0 = bfv_to_f4(*reinterpret_cast<const u16x4*>(&hp[(size_t)i0.y * D + c * 4]));
                float4 h1 = bfv_to_f4(*reinterpret_cast<const u16x4*>(&hp[(size_t)i1.y * D + c * 4]));
                float4 h2 = bfv_to_f4(*reinterpret_cast<const u16x4*>(&hp[(size_t)i2.y * D + c * 4]));
                float4 h3 = bfv_to_f4(*reinterpret_cast<const u16x4*>(&hp[(size_t)i3.y * D + c * 4]));
                acc.x += fmaxf(f0[0] + h0.x, 0.f) + fmaxf(f1[0] + h1.x, 0.f)
                       + fmaxf(f2[0] + h2.x, 0.f) + fmaxf(f3[0] + h3.x, 0.f);
                acc.y += fmaxf(f0[1] + h0.y, 0.f) + fmaxf(f1[1] + h1.y, 0.f)
                       + fmaxf(f2[1] + h2.y, 0.f) + fmaxf(f3[1] + h3.y, 0.f);
                acc.z += fmaxf(f0[2] + h0.z, 0.f) + fmaxf(f1[2] + h1.z, 0.f)
                       + fmaxf(f2[2] + h2.z, 0.f) + fmaxf(f3[2] + h3.z, 0.f);
                acc.w += fmaxf(f0[3] + h0.w, 0.f) + fmaxf(f1[3] + h1.w, 0.f)
                       + fmaxf(f2[3] + h2.w, 0.f) + fmaxf(f3[3] + h3.w, 0.f);
            }
            for (; p < pEnd; ++p) {
                int2 i0 = eids2[p];
                f32x4 f0 = __builtin_nontemporal_load(
                    reinterpret_cast<const f32x4*>(&ef[(size_t)i0.x * D + c * 4]));
                float4 h0 = bfv_to_f4(*reinterpret_cast<const u16x4*>(&hp[(size_t)i0.y * D + c * 4]));
                acc.x += fmaxf(f0[0] + h0.x, 0.f);
                acc.y += fmaxf(f0[1] + h0.y, 0.f);
                acc.z += fmaxf(f0[2] + h0.z, 0.f);
                acc.w += fmaxf(f0[3] + h0.w, 0.f);
            }
            u16x4 o;
            o.x = f2bf(h.x + acc.x);
            o.y = f2bf(h.y + acc.y);
            o.z = f2bf(h.z + acc.z);
            o.w = f2bf(h.w + acc.w);
            *reinterpret_cast<u16x4*>(&zs[nl][c * 4]) = o;
        }
    }
    __syncthreads();

    // ---- MLP phase (R4-verified MFMA body; A-fragments from LDS z tile)
    const int wave = tid >> 6, lane = tid & 63;
    const int lr = lane & 15, lg = lane >> 4;
    const int m0w = m0 + wave * 16;

    bf16x8 a1[4];
    int lrow = wave * 16 + lr;
    if (m0 + lrow > N - 1) lrow = N - 1 - m0;   // clamp to a gathered local row
#pragma unroll
    for (int kb = 0; kb < 4; ++kb)
        a1[kb] = *reinterpret_cast<const bf16x8*>(&zs[lrow][kb * 32 + lg * 8]);

#pragma unroll
    for (int nb = 0; nb < 16; ++nb) {
        f32x4 c = {0.f, 0.f, 0.f, 0.f};
#pragma unroll
        for (int kb = 0; kb < 4; ++kb) {
            bf16x8 b = *reinterpret_cast<const bf16x8*>(&w1p[((kb * 16 + nb) * 64 + lane) * 8]);
            c = __builtin_amdgcn_mfma_f32_16x16x32_bf16(a1[kb], b, c, 0, 0, 0);
        }
        float bias = b1[nb * 16 + lr];
#pragma unroll
        for (int r = 0; r < 4; ++r) {
            float v = fmaxf(c[r] + bias, 0.f);
            u_lds[wave][lg * 4 + r][nb * 16 + lr] = f2bf(v);
        }
    }
    __syncthreads();

    bf16x8 a2[8];
#pragma unroll
    for (int kb = 0; kb < 8; ++kb)
        a2[kb] = *reinterpret_cast<const bf16x8*>(&u_lds[wave][lr][kb * 32 + lg * 8]);

#pragma unroll
    for (int nb = 0; nb < 8; ++nb) {
        f32x4 c = {0.f, 0.f, 0.f, 0.f};
#pragma unroll
        for (int kb = 0; kb < 8; ++kb) {
            bf16x8 b = *reinterpret_cast<const bf16x8*>(&w2p[((kb * 8 + nb) * 64 + lane) * 8]);
            c = __builtin_amdgcn_mfma_f32_16x16x32_bf16(a2[kb], b, c, 0, 0, 0);
        }
        float bias = b2[nb * 16 + lr];
#pragma unroll
        for (int r = 0; r < 4; ++r) {
            int row = m0w + lg * 4 + r;
            if (row < N) out[(size_t)row * DUP + nb * 16 + lr] = c[r] + bias;
        }
    }
}

// ---------------------------------------------------------------- launch
extern "C" void kernel_launch(void* const* d_in, const int* in_sizes, int n_in,
                              void* d_out, int out_size, void* d_ws, size_t ws_size,
                              hipStream_t stream) {
    const float* x   = (const float*)d_in[0];
    const float* dg  = (const float*)d_in[1];
    const float* ef  = (const float*)d_in[2];
    const float* W1  = (const float*)d_in[3];
    const float* b1  = (const float*)d_in[4];
    const float* W2  = (const float*)d_in[5];
    const float* b2  = (const float*)d_in[6];
    const int*   ei  = (const int*)d_in[7];
    float* out = (float*)d_out;

    const int N = in_sizes[0] / DIN;       // 50000
    const int E = in_sizes[7] / 2;         // 800000

    auto align16 = [](size_t v) { return (v + 15) & ~(size_t)15; };
    char* w = (char*)d_ws;
    ushort* hp      = (ushort*)w;  w += align16((size_t)N * D * 2);
    int*   counts   = (int*)w;     w += align16((size_t)N * 4);
    int*   offsets  = (int*)w;     w += align16((size_t)(N + 1) * 4);
    int*   cursor   = (int*)w;     w += align16((size_t)N * 4);
    int2*  eids2    = (int2*)w;    w += align16((size_t)E * 8);
    int*   blockSums= (int*)w;     w += align16(64 * 4);
    int*   blockBase= (int*)w;     w += align16(64 * 4);
    ushort* w1p     = (ushort*)w;  w += align16((size_t)D * DH * 2);
    ushort* w2p     = (ushort*)w;  w += align16((size_t)DH * DUP * 2);

    const int eb = (E + 255) / 256;
    const int nbScan = (N + 1023) / 1024;   // 49

    init_h_kernel<<<(N * 32 + 255) / 256, 256, 0, stream>>>(
        x, dg, W1, W2, hp, w1p, w2p, counts, N);
    count_kernel<<<eb, 256, 0, stream>>>(ei, counts, N, E);
    scan_partial_kernel<<<nbScan, 256, 0, stream>>>(counts, blockSums, N);
    scan_base_kernel<<<1, 64, 0, stream>>>(blockSums, blockBase, nbScan);
    scan_final_kernel<<<nbScan, 256, 0, stream>>>(counts, blockBase, offsets, cursor, N, E);
    fill_kernel<<<eb, 256, 0, stream>>>(ei, cursor, eids2, E);

    gather_mlp_kernel<<<(N + 63) / 64, 256, 0, stream>>>(
        hp, ef, offsets, eids2, w1p, b1, w2p, b2, out, N);
}

// Round 9
// 239.359 us; speedup vs baseline: 5.6625x; 1.1913x over previous
//
#include <hip/hip_runtime.h>

// MPNN_edge_sparse_ogb — round 8: consolidate on R4 structure (best: 242.7 µs).
//  - gather: R4's half-wave/node, 4-wide unroll, 6250 blocks (fusion in R7 lost
//    8x gather TLP -> +42 µs; reverted).
//  - init folds: hp pack + weight pack + counts zero (-1 dispatch vs R4)
//  - scan_base folded into scan_final (each block wave-reduces its own base, -1 dispatch)
// Pipeline: init -> count -> scan_partial -> scan_final -> fill -> gather -> mlp (7 dispatches)
// ws: zb | hp | counts | offsets | cursor | eids2[E]int2 | blockSums | w1p | w2p

constexpr int DIN  = 96;
constexpr int DDEG = 32;
constexpr int D    = 128;
constexpr int DH   = 256;
constexpr int DUP  = 128;

typedef short bf16x8 __attribute__((ext_vector_type(8)));
typedef float f32x4  __attribute__((ext_vector_type(4)));
typedef unsigned short u16x4 __attribute__((ext_vector_type(4)));

static __device__ __forceinline__ ushort f2bf(float f) {
    unsigned u = __float_as_uint(f);
    unsigned r = (u + 0x7fff + ((u >> 16) & 1)) >> 16;   // RNE
    return (ushort)r;
}
static __device__ __forceinline__ float4 bfv_to_f4(u16x4 u) {
    float4 r;
    r.x = __uint_as_float((unsigned)u.x << 16);
    r.y = __uint_as_float((unsigned)u.y << 16);
    r.z = __uint_as_float((unsigned)u.z << 16);
    r.w = __uint_as_float((unsigned)u.w << 16);
    return r;
}
static __device__ __forceinline__ int waveInclScan(int v, int lane) {
#pragma unroll
    for (int off = 1; off < 64; off <<= 1) {
        int t = __shfl_up(v, off, 64);
        if (lane >= off) v += t;
    }
    return v;
}

// ---------------------------------------------------------------- 0. init: hp pack + weight pack + zero counts
__global__ __launch_bounds__(256) void init_h_kernel(
    const float* __restrict__ x, const float* __restrict__ deg,
    const float* __restrict__ W1, const float* __restrict__ W2,
    ushort* __restrict__ hp, ushort* __restrict__ w1p, ushort* __restrict__ w2p,
    int* __restrict__ counts, int N) {
    int t = blockIdx.x * 256 + threadIdx.x;
    if (t < (N >> 2)) *reinterpret_cast<int4*>(&counts[t * 4]) = make_int4(0, 0, 0, 0);
    if (t == (N >> 2) && (N & 3)) {
        for (int i = (N & ~3); i < N; ++i) counts[i] = 0;
    }
    if (t < 32768) {
        {   // w1p[((kb*16+nb)*64+l)*8+j] = bf16(W1[kb*32+(l>>4)*8+j][nb*16+(l&15)])
            int j = t & 7, l = (t >> 3) & 63, nb = (t >> 9) & 15, kb = t >> 13;
            w1p[t] = f2bf(W1[(kb * 32 + (l >> 4) * 8 + j) * DH + nb * 16 + (l & 15)]);
        }
        {   // w2p: kb<8, nb<8
            int j = t & 7, l = (t >> 3) & 63, nb = (t >> 9) & 7, kb = t >> 12;
            w2p[t] = f2bf(W2[(kb * 32 + (l >> 4) * 8 + j) * DUP + nb * 16 + (l & 15)]);
        }
    }
    if (t >= N * 32) return;
    int n = t >> 5, c = t & 31;
    float4 v;
    if (c < 24) v = *reinterpret_cast<const float4*>(&x[(size_t)n * DIN + c * 4]);
    else        v = *reinterpret_cast<const float4*>(&deg[(size_t)n * DDEG + (c - 24) * 4]);
    u16x4 o;
    o.x = f2bf(v.x); o.y = f2bf(v.y); o.z = f2bf(v.z); o.w = f2bf(v.w);
    *reinterpret_cast<u16x4*>(&hp[(size_t)n * D + c * 4]) = o;
}

// ---------------------------------------------------------------- 1. count in-degrees
__global__ __launch_bounds__(256) void count_kernel(
    const int* __restrict__ ei, int* __restrict__ counts, int N, int E) {
    int e = blockIdx.x * 256 + threadIdx.x;
    if (e >= E) return;
    atomicAdd(&counts[ei[E + e]], 1);
}

// ---------------------------------------------------------------- 2a. per-1024-block sums
__global__ __launch_bounds__(256) void scan_partial_kernel(
    const int* __restrict__ counts, int* __restrict__ blockSums, int N) {
    const int tid = threadIdx.x;
    int base = blockIdx.x * 1024 + tid * 4;
    int4 c = make_int4(0, 0, 0, 0);
    if (base + 3 < N) c = *reinterpret_cast<const int4*>(&counts[base]);
    else if (base < N) {
        c.x = counts[base];
        if (base + 1 < N) c.y = counts[base + 1];
        if (base + 2 < N) c.z = counts[base + 2];
    }
    int s = c.x + c.y + c.z + c.w;
#pragma unroll
    for (int off = 32; off; off >>= 1) s += __shfl_xor(s, off, 64);
    __shared__ int wsum[4];
    if ((tid & 63) == 0) wsum[tid >> 6] = s;
    __syncthreads();
    if (tid == 0) blockSums[blockIdx.x] = wsum[0] + wsum[1] + wsum[2] + wsum[3];
}

// ---------------------------------------------------------------- 2b. final scan (self-computed base) -> offsets/cursor
__global__ __launch_bounds__(256) void scan_final_kernel(
    const int* __restrict__ counts, const int* __restrict__ blockSums,
    int* __restrict__ offsets, int* __restrict__ cursor, int N, int E, int nbScan) {
    const int tid = threadIdx.x, lane = tid & 63, wave = tid >> 6;
    __shared__ int sBase;
    __shared__ int wsum[4];

    // wave 0: base = sum of blockSums[j], j < blockIdx.x  (nbScan <= 64)
    if (wave == 0) {
        int v = (lane < blockIdx.x && lane < nbScan) ? blockSums[lane] : 0;
#pragma unroll
        for (int off = 32; off; off >>= 1) v += __shfl_xor(v, off, 64);
        if (lane == 0) sBase = v;
    }

    int base = blockIdx.x * 1024 + tid * 4;
    int4 c = make_int4(0, 0, 0, 0);
    if (base + 3 < N) c = *reinterpret_cast<const int4*>(&counts[base]);
    else if (base < N) {
        c.x = counts[base];
        if (base + 1 < N) c.y = counts[base + 1];
        if (base + 2 < N) c.z = counts[base + 2];
    }
    int s = c.x + c.y + c.z + c.w;
    int incl = waveInclScan(s, lane);
    if (lane == 63) wsum[wave] = incl;
    __syncthreads();
    int wb = 0;
#pragma unroll
    for (int w = 0; w < 4; ++w)
        if (w < wave) wb += wsum[w];
    int ex = sBase + wb + (incl - s);
    if (base < N)     { offsets[base]     = ex; cursor[base]     = ex; } ex += c.x;
    if (base + 1 < N) { offsets[base + 1] = ex; cursor[base + 1] = ex; } ex += c.y;
    if (base + 2 < N) { offsets[base + 2] = ex; cursor[base + 2] = ex; } ex += c.z;
    if (base + 3 < N) { offsets[base + 3] = ex; cursor[base + 3] = ex; }
    if (blockIdx.x == 0 && tid == 0) offsets[N] = E;
}

// ---------------------------------------------------------------- 3. fill CSR payload {e, src}
__global__ __launch_bounds__(256) void fill_kernel(
    const int* __restrict__ ei, int* __restrict__ cursor,
    int2* __restrict__ eids2, int E) {
    int e = blockIdx.x * 256 + threadIdx.x;
    if (e >= E) return;
    int src = ei[e];
    int dst = ei[E + e];
    int pos = atomicAdd(&cursor[dst], 1);
    eids2[pos] = make_int2(e, src);
}

// ---------------------------------------------------------------- 4. gather (R4): half-wave/node, 4-wide unroll
__global__ __launch_bounds__(256) void gather_kernel(
    const ushort* __restrict__ hp, const float* __restrict__ ef,
    const int* __restrict__ offsets, const int2* __restrict__ eids2,
    ushort* __restrict__ zb, int N) {
    const int node = blockIdx.x * 8 + (threadIdx.x >> 5);
    if (node >= N) return;
    const int c = threadIdx.x & 31;   // float4 chunk 0..31

    float4 h = bfv_to_f4(*reinterpret_cast<const u16x4*>(&hp[(size_t)node * D + c * 4]));

    float4 acc = make_float4(0.f, 0.f, 0.f, 0.f);
    const int pEnd = offsets[node + 1];
    int p = offsets[node];

    for (; p + 4 <= pEnd; p += 4) {
        int2 i0 = eids2[p + 0];
        int2 i1 = eids2[p + 1];
        int2 i2 = eids2[p + 2];
        int2 i3 = eids2[p + 3];
        f32x4 f0 = __builtin_nontemporal_load(
            reinterpret_cast<const f32x4*>(&ef[(size_t)i0.x * D + c * 4]));
        f32x4 f1 = __builtin_nontemporal_load(
            reinterpret_cast<const f32x4*>(&ef[(size_t)i1.x * D + c * 4]));
        f32x4 f2 = __builtin_nontemporal_load(
            reinterpret_cast<const f32x4*>(&ef[(size_t)i2.x * D + c * 4]));
        f32x4 f3 = __builtin_nontemporal_load(
            reinterpret_cast<const f32x4*>(&ef[(size_t)i3.x * D + c * 4]));
        float4 h0 = bfv_to_f4(*reinterpret_cast<const u16x4*>(&hp[(size_t)i0.y * D + c * 4]));
        float4 h1 = bfv_to_f4(*reinterpret_cast<const u16x4*>(&hp[(size_t)i1.y * D + c * 4]));
        float4 h2 = bfv_to_f4(*reinterpret_cast<const u16x4*>(&hp[(size_t)i2.y * D + c * 4]));
        float4 h3 = bfv_to_f4(*reinterpret_cast<const u16x4*>(&hp[(size_t)i3.y * D + c * 4]));
        acc.x += fmaxf(f0[0] + h0.x, 0.f) + fmaxf(f1[0] + h1.x, 0.f)
               + fmaxf(f2[0] + h2.x, 0.f) + fmaxf(f3[0] + h3.x, 0.f);
        acc.y += fmaxf(f0[1] + h0.y, 0.f) + fmaxf(f1[1] + h1.y, 0.f)
               + fmaxf(f2[1] + h2.y, 0.f) + fmaxf(f3[1] + h3.y, 0.f);
        acc.z += fmaxf(f0[2] + h0.z, 0.f) + fmaxf(f1[2] + h1.z, 0.f)
               + fmaxf(f2[2] + h2.z, 0.f) + fmaxf(f3[2] + h3.z, 0.f);
        acc.w += fmaxf(f0[3] + h0.w, 0.f) + fmaxf(f1[3] + h1.w, 0.f)
               + fmaxf(f2[3] + h2.w, 0.f) + fmaxf(f3[3] + h3.w, 0.f);
    }
    for (; p < pEnd; ++p) {
        int2 i0 = eids2[p];
        f32x4 f0 = __builtin_nontemporal_load(
            reinterpret_cast<const f32x4*>(&ef[(size_t)i0.x * D + c * 4]));
        float4 h0 = bfv_to_f4(*reinterpret_cast<const u16x4*>(&hp[(size_t)i0.y * D + c * 4]));
        acc.x += fmaxf(f0[0] + h0.x, 0.f);
        acc.y += fmaxf(f0[1] + h0.y, 0.f);
        acc.z += fmaxf(f0[2] + h0.z, 0.f);
        acc.w += fmaxf(f0[3] + h0.w, 0.f);
    }
    u16x4 o;
    o.x = f2bf(h.x + acc.x);
    o.y = f2bf(h.y + acc.y);
    o.z = f2bf(h.z + acc.z);
    o.w = f2bf(h.w + acc.w);
    *reinterpret_cast<u16x4*>(&zb[(size_t)node * D + c * 4]) = o;
}

// ---------------------------------------------------------------- 5. MFMA MLP: 64 nodes/block, 16/wave
__global__ __launch_bounds__(256) void mlp_mfma_kernel(
    const ushort* __restrict__ zb,
    const ushort* __restrict__ w1p, const float* __restrict__ b1,
    const ushort* __restrict__ w2p, const float* __restrict__ b2,
    float* __restrict__ out, int N) {
    __shared__ ushort u_lds[4][16][DH + 8];
    const int tid = threadIdx.x;
    const int wave = tid >> 6, lane = tid & 63;
    const int m0 = blockIdx.x * 64 + wave * 16;
    const int lr = lane & 15, lg = lane >> 4;

    bf16x8 a1[4];
    int rowA = m0 + lr; if (rowA > N - 1) rowA = N - 1;
    const ushort* zrow = &zb[(size_t)rowA * D + lg * 8];
#pragma unroll
    for (int kb = 0; kb < 4; ++kb)
        a1[kb] = *reinterpret_cast<const bf16x8*>(zrow + kb * 32);

#pragma unroll
    for (int nb = 0; nb < 16; ++nb) {
        f32x4 c = {0.f, 0.f, 0.f, 0.f};
#pragma unroll
        for (int kb = 0; kb < 4; ++kb) {
            bf16x8 b = *reinterpret_cast<const bf16x8*>(&w1p[((kb * 16 + nb) * 64 + lane) * 8]);
            c = __builtin_amdgcn_mfma_f32_16x16x32_bf16(a1[kb], b, c, 0, 0, 0);
        }
        float bias = b1[nb * 16 + lr];
#pragma unroll
        for (int r = 0; r < 4; ++r) {
            float v = fmaxf(c[r] + bias, 0.f);
            u_lds[wave][lg * 4 + r][nb * 16 + lr] = f2bf(v);
        }
    }
    __syncthreads();

    bf16x8 a2[8];
#pragma unroll
    for (int kb = 0; kb < 8; ++kb)
        a2[kb] = *reinterpret_cast<const bf16x8*>(&u_lds[wave][lr][kb * 32 + lg * 8]);

#pragma unroll
    for (int nb = 0; nb < 8; ++nb) {
        f32x4 c = {0.f, 0.f, 0.f, 0.f};
#pragma unroll
        for (int kb = 0; kb < 8; ++kb) {
            bf16x8 b = *reinterpret_cast<const bf16x8*>(&w2p[((kb * 8 + nb) * 64 + lane) * 8]);
            c = __builtin_amdgcn_mfma_f32_16x16x32_bf16(a2[kb], b, c, 0, 0, 0);
        }
        float bias = b2[nb * 16 + lr];
#pragma unroll
        for (int r = 0; r < 4; ++r) {
            int row = m0 + lg * 4 + r;
            if (row < N) out[(size_t)row * DUP + nb * 16 + lr] = c[r] + bias;
        }
    }
}

// ---------------------------------------------------------------- launch
extern "C" void kernel_launch(void* const* d_in, const int* in_sizes, int n_in,
                              void* d_out, int out_size, void* d_ws, size_t ws_size,
                              hipStream_t stream) {
    const float* x   = (const float*)d_in[0];
    const float* dg  = (const float*)d_in[1];
    const float* ef  = (const float*)d_in[2];
    const float* W1  = (const float*)d_in[3];
    const float* b1  = (const float*)d_in[4];
    const float* W2  = (const float*)d_in[5];
    const float* b2  = (const float*)d_in[6];
    const int*   ei  = (const int*)d_in[7];
    float* out = (float*)d_out;

    const int N = in_sizes[0] / DIN;       // 50000
    const int E = in_sizes[7] / 2;         // 800000

    auto align16 = [](size_t v) { return (v + 15) & ~(size_t)15; };
    char* w = (char*)d_ws;
    ushort* zb      = (ushort*)w;  w += align16((size_t)N * D * 2);
    ushort* hp      = (ushort*)w;  w += align16((size_t)N * D * 2);
    int*   counts   = (int*)w;     w += align16((size_t)N * 4);
    int*   offsets  = (int*)w;     w += align16((size_t)(N + 1) * 4);
    int*   cursor   = (int*)w;     w += align16((size_t)N * 4);
    int2*  eids2    = (int2*)w;    w += align16((size_t)E * 8);
    int*   blockSums= (int*)w;     w += align16(64 * 4);
    ushort* w1p     = (ushort*)w;  w += align16((size_t)D * DH * 2);
    ushort* w2p     = (ushort*)w;  w += align16((size_t)DH * DUP * 2);

    const int eb = (E + 255) / 256;
    const int nbScan = (N + 1023) / 1024;   // 49

    init_h_kernel<<<(N * 32 + 255) / 256, 256, 0, stream>>>(
        x, dg, W1, W2, hp, w1p, w2p, counts, N);
    count_kernel<<<eb, 256, 0, stream>>>(ei, counts, N, E);
    scan_partial_kernel<<<nbScan, 256, 0, stream>>>(counts, blockSums, N);
    scan_final_kernel<<<nbScan, 256, 0, stream>>>(counts, blockSums, offsets, cursor, N, E, nbScan);
    fill_kernel<<<eb, 256, 0, stream>>>(ei, cursor, eids2, E);

    gather_kernel<<<(N + 7) / 8, 256, 0, stream>>>(hp, ef, offsets, eids2, zb, N);

    mlp_mfma_kernel<<<(N + 63) / 64, 256, 0, stream>>>(zb, w1p, b1, w2p, b2, out, N);
}